// Round 3
// baseline (1715.871 us; speedup 1.0000x reference)
//
#include <hip/hip_runtime.h>

#define T_STEPS 512
#define INPUT   13
#define HIDDEN  64
#define NGATES  256   // 4*HIDDEN
#define MB      4     // batch rows per block: grid 1024 -> 4 blocks/CU
#define CS      16    // timesteps per x-chunk
#define XPAD    16    // padded input dim (13 -> 16)
#define NCHUNK  (T_STEPS / CS)
#define NTHREADS 512  // 256 gates x 2 halves

__device__ __forceinline__ float sigmoid_f(float x) {
    return 1.0f / (1.0f + __expf(-x));
}
__device__ __forceinline__ float tanh_f(float x) {
    // tanh(x) = 1 - 2/(1+exp(2x)); saturates correctly for large |x|
    return 1.0f - 2.0f / (1.0f + __expf(2.0f * x));
}

// Split-gate layout: thread (g, half) owns HALF of gate g's weight rows:
//   wh[32] = W_hh[g][half*32 .. half*32+31],  wi[8] = padded W_ih[g][half*8 ..]
// Per-thread register demand ~60 -> fits the allocator's preferred 8-waves/EU
// tier (<=64 VGPR), so weights stay resident with NO per-step reloads (the
// round-1/2 bottleneck: VGPR_Count=60 < 77 weights => ~40 reloads/step).
// Halves combine with one __shfl_xor(acc,1) per row (DPP quad-perm, 2 cyc).
// launch_bounds(512,6): 85-VGPR ceiling as margin; allocator can still land
// <=64 and run 8 waves/EU (4 blocks/CU, 32 waves/CU).
__global__
__launch_bounds__(NTHREADS, 6)
void lstm_fused_kernel(const float* __restrict__ x,
                       const float* __restrict__ W_ih,
                       const float* __restrict__ W_hh,
                       const float* __restrict__ b_ih,
                       const float* __restrict__ b_hh,
                       const float* __restrict__ W_fc,
                       const float* __restrict__ b_fc,
                       float* __restrict__ out)
{
    __shared__ float xs[2][MB][CS][XPAD];   // 8 KB: double-buffered x chunks
    __shared__ float hl[MB][HIDDEN];        // 1 KB: hidden state
    __shared__ float gl[MB][NGATES];        // 4 KB: gate pre-activations

    const int tid  = threadIdx.x;
    const int g    = tid >> 1;              // gate 0..255
    const int half = tid & 1;               // which half of the dot product
    const int row0 = blockIdx.x * MB;

    // ---- per-thread weights: half a gate row ----
    float wi[8];
    #pragma unroll
    for (int i = 0; i < 8; ++i) {
        const int idx = half * 8 + i;       // 0..15 (13..15 are pad)
        wi[i] = (idx < INPUT) ? W_ih[g * INPUT + idx] : 0.0f;
    }

    float wh[32];
    #pragma unroll
    for (int j = 0; j < 32; ++j)
        wh[j] = W_hh[g * HIDDEN + half * 32 + j];

    // bias only on half 0 so the pair-sum counts it once
    const float bias = half ? 0.0f : (b_ih[g] + b_hh[g]);

    // ---- init h (LDS) and c (reg, threads 0..255 own cell (r,k)) ----
    if (tid < MB * HIDDEN)
        hl[tid >> 6][tid & 63] = 0.0f;
    float c0 = 0.0f;

    // ---- x chunk loader: [MB][CS][XPAD] = 1024 floats, 2 elems/thread ----
    float stg[2];
    auto load_chunk = [&](int c) {
        #pragma unroll
        for (int k = 0; k < 2; ++k) {
            int idx = tid + k * NTHREADS;   // 0..1023
            int r   = idx >> 8;             // /(CS*XPAD)
            int rem = idx & 255;
            int tt  = rem >> 4;
            int i   = rem & 15;
            float v = 0.0f;
            if (i < INPUT)
                v = x[(size_t)(row0 + r) * (T_STEPS * INPUT)
                      + (size_t)(c * CS + tt) * INPUT + i];
            stg[k] = v;
        }
    };
    auto store_chunk = [&](int buf) {
        #pragma unroll
        for (int k = 0; k < 2; ++k) {
            int idx = tid + k * NTHREADS;
            ((float*)xs[buf])[idx] = stg[k];
        }
    };

    load_chunk(0);
    store_chunk(0);
    __syncthreads();

    for (int cidx = 0; cidx < NCHUNK; ++cidx) {
        const int cur = cidx & 1;
        if (cidx + 1 < NCHUNK)
            load_chunk(cidx + 1);   // issue early; consumed after step loop

        #pragma unroll 1
        for (int tt = 0; tt < CS; ++tt) {
            // ---- partial gates: acc[r] = bias + x_half.wi + h_half.wh ----
            float acc[MB];
            #pragma unroll
            for (int r = 0; r < MB; ++r) acc[r] = bias;

            // x part: this half's 8 padded inputs = 2 float4 per row
            // (wave reads only 2 distinct LDS addresses -> broadcast)
            #pragma unroll
            for (int q = 0; q < 2; ++q) {
                #pragma unroll
                for (int r = 0; r < MB; ++r) {
                    const float4 xv = *(const float4*)&xs[cur][r][tt][half * 8 + q * 4];
                    acc[r] = fmaf(xv.x, wi[q * 4 + 0], acc[r]);
                    acc[r] = fmaf(xv.y, wi[q * 4 + 1], acc[r]);
                    acc[r] = fmaf(xv.z, wi[q * 4 + 2], acc[r]);
                    acc[r] = fmaf(xv.w, wi[q * 4 + 3], acc[r]);
                }
            }

            // h part: this half's 32 h values = 8 float4 per row (broadcast)
            #pragma unroll
            for (int q = 0; q < 8; ++q) {
                #pragma unroll
                for (int r = 0; r < MB; ++r) {
                    const float4 hv = *(const float4*)&hl[r][half * 32 + q * 4];
                    acc[r] = fmaf(hv.x, wh[q * 4 + 0], acc[r]);
                    acc[r] = fmaf(hv.y, wh[q * 4 + 1], acc[r]);
                    acc[r] = fmaf(hv.z, wh[q * 4 + 2], acc[r]);
                    acc[r] = fmaf(hv.w, wh[q * 4 + 3], acc[r]);
                }
            }

            // ---- combine halves within the lane pair (DPP, stays on VALU) ----
            #pragma unroll
            for (int r = 0; r < MB; ++r)
                acc[r] += __shfl_xor(acc[r], 1);

            // even lane of each pair writes the full pre-activation
            if (!half) {
                #pragma unroll
                for (int r = 0; r < MB; ++r)
                    gl[r][g] = acc[r];
            }
            __syncthreads();

            // ---- cell update: threads 0..255 own cell (r = tid>>6, k = tid&63) ----
            if (tid < MB * HIDDEN) {
                const int k = tid & 63;
                const int r = tid >> 6;          // 0..3
                float ig = sigmoid_f(gl[r][k]);
                float fg = sigmoid_f(gl[r][64 + k]);
                float gg = tanh_f   (gl[r][128 + k]);
                float og = sigmoid_f(gl[r][192 + k]);
                c0 = fg * c0 + ig * gg;
                hl[r][k] = og * tanh_f(c0);
            }
            __syncthreads();
        }

        if (cidx + 1 < NCHUNK) {
            store_chunk(1 - cur);   // waits on the global loads issued above
            __syncthreads();
        }
    }

    // ---- epilogue: out[row] = sigmoid(h_T . W_fc + b_fc) ----
    if (tid < MB) {
        float acc = b_fc[0];
        #pragma unroll
        for (int j = 0; j < HIDDEN; ++j)
            acc = fmaf(hl[tid][j], W_fc[j], acc);
        out[row0 + tid] = sigmoid_f(acc);
    }
}

extern "C" void kernel_launch(void* const* d_in, const int* in_sizes, int n_in,
                              void* d_out, int out_size, void* d_ws, size_t ws_size,
                              hipStream_t stream) {
    const float* x    = (const float*)d_in[0];
    const float* W_ih = (const float*)d_in[1];
    const float* W_hh = (const float*)d_in[2];
    const float* b_ih = (const float*)d_in[3];
    const float* b_hh = (const float*)d_in[4];
    const float* W_fc = (const float*)d_in[5];
    const float* b_fc = (const float*)d_in[6];
    float* out = (float*)d_out;

    const int B = 4096;
    dim3 grid(B / MB), block(NTHREADS);
    lstm_fused_kernel<<<grid, block, 0, stream>>>(x, W_ih, W_hh, b_ih, b_hh,
                                                  W_fc, b_fc, out);
}

// Round 4
// 1630.943 us; speedup vs baseline: 1.0521x; 1.0521x over previous
//
#include <hip/hip_runtime.h>

#define T_STEPS 512
#define INPUT   13
#define HIDDEN  64
#define NGATES  256   // 4*HIDDEN
#define MB      4     // batch rows per block: grid 1024 -> 4 blocks/CU
#define CS      16    // timesteps per x-chunk
#define XPAD    16    // padded input dim (13 -> 16)
#define NCHUNK  (T_STEPS / CS)

__device__ __forceinline__ float sigmoid_f(float x) {
    return 1.0f / (1.0f + __expf(-x));
}
__device__ __forceinline__ float tanh_f(float x) {
    // tanh(x) = 1 - 2/(1+exp(2x)); saturates correctly for large |x|
    return 1.0f - 2.0f / (1.0f + __expf(2.0f * x));
}

// Register-residency by construction:
//  - amdgpu_waves_per_eu(4,4): VGPR budget = 512/4 = 128 >= ~102 demand.
//    (no __launch_bounds__ -- rounds 1-3 showed the allocator sinks the
//    weight loads into the loop and allocates BELOW demand: 76/60/40 VGPR
//    for 105/95/55-reg demand, ~1.8 extra VALU ops per FMA re-loading them.)
//  - asm "+v" pins INSIDE the chunk loop: the asm nominally writes each
//    weight, so re-loading it from W_ih/W_hh later is ILLEGAL (memory no
//    longer provably holds the value). Values must stay register-carried
//    across the whole loop nest. Pin cost: 0 instructions, 32 executions.
__global__
__attribute__((amdgpu_flat_work_group_size(256, 256), amdgpu_waves_per_eu(4, 4)))
void lstm_fused_kernel(const float* __restrict__ x,
                       const float* __restrict__ W_ih,
                       const float* __restrict__ W_hh,
                       const float* __restrict__ b_ih,
                       const float* __restrict__ b_hh,
                       const float* __restrict__ W_fc,
                       const float* __restrict__ b_fc,
                       float* __restrict__ out)
{
    __shared__ float xs[2][MB][CS][XPAD];   // 8 KB: double-buffered x chunks
    __shared__ float hl[MB][HIDDEN];        // 1 KB: hidden state
    __shared__ float gl[MB][NGATES];        // 4 KB: gate pre-activations

    const int tid  = threadIdx.x;
    const int row0 = blockIdx.x * MB;

    // ---- per-thread weights: this thread owns gate g = tid ----
    float wi[INPUT];
    #pragma unroll
    for (int i = 0; i < INPUT; ++i)
        wi[i] = W_ih[tid * INPUT + i];

    float wh[HIDDEN];
    #pragma unroll
    for (int j = 0; j < HIDDEN; ++j)
        wh[j] = W_hh[tid * HIDDEN + j];

    float bias = b_ih[tid] + b_hh[tid];

    // ---- init h (LDS, one element per thread) and c (reg) ----
    hl[tid >> 6][tid & 63] = 0.0f;
    float c0 = 0.0f;

    // ---- x chunk loader: [MB][CS][XPAD] = 1024 floats, 4 elems/thread ----
    float stg[4];
    auto load_chunk = [&](int c) {
        #pragma unroll
        for (int k = 0; k < 4; ++k) {
            int idx = tid + k * 256;        // 0..1023
            int r   = idx >> 8;             // /(CS*XPAD)
            int rem = idx & 255;
            int tt  = rem >> 4;
            int i   = rem & 15;
            float v = 0.0f;
            if (i < INPUT)
                v = x[(size_t)(row0 + r) * (T_STEPS * INPUT)
                      + (size_t)(c * CS + tt) * INPUT + i];
            stg[k] = v;
        }
    };
    auto store_chunk = [&](int buf) {
        #pragma unroll
        for (int k = 0; k < 4; ++k) {
            int idx = tid + k * 256;
            ((float*)xs[buf])[idx] = stg[k];
        }
    };

    load_chunk(0);
    store_chunk(0);
    __syncthreads();

    for (int cidx = 0; cidx < NCHUNK; ++cidx) {
        // ---- PIN weights in VGPRs for this iteration and all later uses.
        // Inside the loop => re-loads from global are illegal from here on.
        #pragma unroll
        for (int i = 0; i < INPUT; ++i)
            asm volatile("" : "+v"(wi[i]));
        #pragma unroll
        for (int j = 0; j < HIDDEN; ++j)
            asm volatile("" : "+v"(wh[j]));
        asm volatile("" : "+v"(bias));

        const int cur = cidx & 1;
        if (cidx + 1 < NCHUNK)
            load_chunk(cidx + 1);   // issue early; consumed after step loop

        #pragma unroll 1
        for (int tt = 0; tt < CS; ++tt) {
            // ---- gates: acc[r] = bias + x.Wih_row + h.Whh_row ----
            float acc[MB];
            #pragma unroll
            for (int r = 0; r < MB; ++r) acc[r] = bias;

            // x part: 13 real inputs = 3 float4 + 1 scalar per row
            #pragma unroll
            for (int q = 0; q < 3; ++q) {
                #pragma unroll
                for (int r = 0; r < MB; ++r) {
                    const float4 xv = *(const float4*)&xs[cur][r][tt][q * 4];
                    acc[r] = fmaf(xv.x, wi[q * 4 + 0], acc[r]);
                    acc[r] = fmaf(xv.y, wi[q * 4 + 1], acc[r]);
                    acc[r] = fmaf(xv.z, wi[q * 4 + 2], acc[r]);
                    acc[r] = fmaf(xv.w, wi[q * 4 + 3], acc[r]);
                }
            }
            #pragma unroll
            for (int r = 0; r < MB; ++r)
                acc[r] = fmaf(xs[cur][r][tt][12], wi[12], acc[r]);

            // h part: 16 float4 per row (wave-uniform address -> broadcast)
            #pragma unroll
            for (int q = 0; q < HIDDEN / 4; ++q) {
                #pragma unroll
                for (int r = 0; r < MB; ++r) {
                    const float4 hv = *(const float4*)&hl[r][q * 4];
                    acc[r] = fmaf(hv.x, wh[q * 4 + 0], acc[r]);
                    acc[r] = fmaf(hv.y, wh[q * 4 + 1], acc[r]);
                    acc[r] = fmaf(hv.z, wh[q * 4 + 2], acc[r]);
                    acc[r] = fmaf(hv.w, wh[q * 4 + 3], acc[r]);
                }
            }
            #pragma unroll
            for (int r = 0; r < MB; ++r)
                gl[r][tid] = acc[r];
            __syncthreads();

            // ---- cell update: thread owns cell (r = tid>>6, k = tid&63) ----
            {
                const int k = tid & 63;
                const int r = tid >> 6;          // 0..3
                float ig = sigmoid_f(gl[r][k]);
                float fg = sigmoid_f(gl[r][64 + k]);
                float gg = tanh_f   (gl[r][128 + k]);
                float og = sigmoid_f(gl[r][192 + k]);
                c0 = fg * c0 + ig * gg;
                hl[r][k] = og * tanh_f(c0);
            }
            __syncthreads();
        }

        if (cidx + 1 < NCHUNK) {
            store_chunk(1 - cur);   // waits on the global loads issued above
            __syncthreads();
        }
    }

    // ---- epilogue: out[row] = sigmoid(h_T . W_fc + b_fc) ----
    if (tid < MB) {
        float acc = b_fc[0];
        #pragma unroll
        for (int j = 0; j < HIDDEN; ++j)
            acc = fmaf(hl[tid][j], W_fc[j], acc);
        out[row0 + tid] = sigmoid_f(acc);
    }
}

extern "C" void kernel_launch(void* const* d_in, const int* in_sizes, int n_in,
                              void* d_out, int out_size, void* d_ws, size_t ws_size,
                              hipStream_t stream) {
    const float* x    = (const float*)d_in[0];
    const float* W_ih = (const float*)d_in[1];
    const float* W_hh = (const float*)d_in[2];
    const float* b_ih = (const float*)d_in[3];
    const float* b_hh = (const float*)d_in[4];
    const float* W_fc = (const float*)d_in[5];
    const float* b_fc = (const float*)d_in[6];
    float* out = (float*)d_out;

    const int B = 4096;
    dim3 grid(B / MB), block(256);
    lstm_fused_kernel<<<grid, block, 0, stream>>>(x, W_ih, W_hh, b_ih, b_hh,
                                                  W_fc, b_fc, out);
}